// Round 16
// baseline (124.221 us; speedup 1.0000x reference)
//
#include <hip/hip_runtime.h>
#include <hip/hip_fp16.h>

#define DD 128
#define KK 20
#define NT 256

typedef unsigned int uint_t;
typedef unsigned short ushort_t;
typedef unsigned char uchar_t;
typedef _Float16 f16x8 __attribute__((ext_vector_type(8)));
typedef _Float16 f16x2 __attribute__((ext_vector_type(2)));
typedef __fp16 h16x2 __attribute__((ext_vector_type(2)));
typedef float f32x4 __attribute__((ext_vector_type(4)));
typedef float f32x2 __attribute__((ext_vector_type(2)));

union UH { __half h; ushort_t s; };
union UF { f16x2 v[4]; uint4 u4; };
union CV { h16x2 a; f16x2 b; };

#if __has_builtin(__builtin_amdgcn_cvt_scalef32_pk_f16_fp8)
#define HAVE_SCALEF32 1
#endif

__device__ __forceinline__ float fast_tanh(float x) {
  const float e = __expf(2.f * x);
  return 1.f - 2.f / (e + 1.f);
}

// convert 8 fp8 (uint2) -> 4 packed f16x2
__device__ __forceinline__ UF f8cvt(const uint2 v) {
  UF r;
#ifdef HAVE_SCALEF32
  r.v[0] = __builtin_amdgcn_cvt_scalef32_pk_f16_fp8(v.x, 1.0f, false);
  r.v[1] = __builtin_amdgcn_cvt_scalef32_pk_f16_fp8(v.x, 1.0f, true);
  r.v[2] = __builtin_amdgcn_cvt_scalef32_pk_f16_fp8(v.y, 1.0f, false);
  r.v[3] = __builtin_amdgcn_cvt_scalef32_pk_f16_fp8(v.y, 1.0f, true);
#else
  f32x2 p;
  CV c;
  p = __builtin_amdgcn_cvt_pk_f32_fp8(v.x, false);
  c.a = __builtin_amdgcn_cvt_pkrtz(p[0], p[1]); r.v[0] = c.b;
  p = __builtin_amdgcn_cvt_pk_f32_fp8(v.x, true);
  c.a = __builtin_amdgcn_cvt_pkrtz(p[0], p[1]); r.v[1] = c.b;
  p = __builtin_amdgcn_cvt_pk_f32_fp8(v.y, false);
  c.a = __builtin_amdgcn_cvt_pkrtz(p[0], p[1]); r.v[2] = c.b;
  p = __builtin_amdgcn_cvt_pk_f32_fp8(v.y, true);
  c.a = __builtin_amdgcn_cvt_pkrtz(p[0], p[1]); r.v[3] = c.b;
#endif
  return r;
}

__device__ __forceinline__ void f8acc(f16x2* a, const uint2 v) {
  const UF r = f8cvt(v);
  a[0] += r.v[0]; a[1] += r.v[1]; a[2] += r.v[2]; a[3] += r.v[3];
}

// accumulate 16 fp8 (uint4) into 8 packed f16x2
__device__ __forceinline__ void f8acc16(f16x2* a, const uint4 v) {
  uint2 lo; lo.x = v.x; lo.y = v.y;
  uint2 hi; hi.x = v.z; hi.y = v.w;
  f8acc(a, lo);
  f8acc(a + 4, hi);
}

__device__ __forceinline__ uint4 packf32x8(const float4 v0, const float4 v1) {
  UH h0, h1, h2, h3, h4, h5, h6, h7;
  h0.h = __float2half_rn(v0.x); h1.h = __float2half_rn(v0.y);
  h2.h = __float2half_rn(v0.z); h3.h = __float2half_rn(v0.w);
  h4.h = __float2half_rn(v1.x); h5.h = __float2half_rn(v1.y);
  h6.h = __float2half_rn(v1.z); h7.h = __float2half_rn(v1.w);
  uint4 o;
  o.x = (uint_t)h0.s | ((uint_t)h1.s << 16);
  o.y = (uint_t)h2.s | ((uint_t)h3.s << 16);
  o.z = (uint_t)h4.s | ((uint_t)h5.s << 16);
  o.w = (uint_t)h6.s | ((uint_t)h7.s << 16);
  return o;
}

// ---------------------------------------------------------------------------
// k_cvt3: three f32 tables -> contiguous fp8 region. 8 elems/thread.
// ---------------------------------------------------------------------------
struct CvtArgs {
  const float* item; const float* loc; const float* timet;
  uchar_t* dst8;
};

__global__ __launch_bounds__(256)
void k_cvt3(CvtArgs a) {
  const int t = blockIdx.x * blockDim.x + threadIdx.x;  // 7000*256
  const float* src;
  if (t < 1600000) src = a.item + (size_t)t * 8;
  else if (t < 1760000) src = a.loc + ((size_t)t - 1600000) * 8;
  else src = a.timet + ((size_t)t - 1760000) * 8;
  const float4* ip = reinterpret_cast<const float4*>(src);
  const float4 x = ip[0], y = ip[1];
  uint_t p0 = __builtin_amdgcn_cvt_pk_fp8_f32(x.x, x.y, 0u, false);
  p0 = __builtin_amdgcn_cvt_pk_fp8_f32(x.z, x.w, p0, true);
  uint_t p1 = __builtin_amdgcn_cvt_pk_fp8_f32(y.x, y.y, 0u, false);
  p1 = __builtin_amdgcn_cvt_pk_fp8_f32(y.z, y.w, p1, true);
  uint2 q; q.x = p0; q.y = p1;
  reinterpret_cast<uint2*>(a.dst8)[t] = q;
}

// ---------------------------------------------------------------------------
// k_pack10: all 10 weight matrices -> MFMA B-fragment order fp16.
// Fragment (kt,nt): lane l, reg j <- W[kt*32 + (l>>4)*8 + j][nt*16 + (l&15)]
// ---------------------------------------------------------------------------
struct PackArgs {
  const float* src[10];
  ushort_t* dst;
};

__global__ __launch_bounds__(256)
void k_pack10(PackArgs a) {
  const int b = blockIdx.x, tid = threadIdx.x;
  int job, tin;
  size_t doff;
  if (b < 112) {
    job = b >> 4; tin = ((b & 15) << 8) | tid;
    doff = (size_t)job * 32768;
  } else {
    job = 7 + ((b - 112) >> 3); tin = (((b - 112) & 7) << 8) | tid;
    doff = 7ull * 32768 + (size_t)(job - 7) * 16384;
  }
  const float* W = a.src[job];
  const int l = tin & 63;
  const int ktnt = tin >> 6;
  const int nt = ktnt & 7;
  const int kt = ktnt >> 3;
  const int col = nt * 16 + (l & 15);
  const int kb = kt * 32 + ((l >> 4) << 3);
  UH h[8];
#pragma unroll
  for (int j = 0; j < 8; ++j) h[j].h = __float2half_rn(W[(size_t)(kb + j) * DD + col]);
  uint4 o;
  o.x = (uint_t)h[0].s | ((uint_t)h[1].s << 16);
  o.y = (uint_t)h[2].s | ((uint_t)h[3].s << 16);
  o.z = (uint_t)h[4].s | ((uint_t)h[5].s << 16);
  o.w = (uint_t)h[6].s | ((uint_t)h[7].s << 16);
  *reinterpret_cast<uint4*>(a.dst + doff + (size_t)ktnt * 512 + l * 8) = o;
}

// ---------------------------------------------------------------------------
// k_mega: 256 threads = 4 waves (wave w -> ntiles {2w,2w+1}).
//  bid <  128 : S path — locs (g=0) / times (g=1), 16 rows, 2 edges+session.
//  bid >= 128 : item path — ONE edge per block (edge=(bid-128)%3), 32 rows.
//  Edge-interleaved blockIdx => each CU hosts a mix of II(L3-fill-bound),
//  TI/LI(L2-hit) and compute-phase blocks — latency hides across blocks
//  (R12-R14 lesson: intra-block register pipelines get demoted to scratch).
//  8 blocks/CU (19.4KB LDS, 4 waves) = 32 waves/CU.
// ---------------------------------------------------------------------------
struct MegaArgs {
  // items
  const int* item_idx; const float* item_f;
  const int* nbI[3]; const uchar_t* embI[3]; const ushort_t* pWI[3]; const float* bI[3];
  const ushort_t* pWsI; const float* bsI; const float* qI;
  ushort_t* hI; float* wsumI;
  // locs (g=0) / times (g=1)
  const int* sidx[2]; const float* st_f[2];
  const int* nbS[2][2]; const uchar_t* embS[2][2];
  const ushort_t* pWS[2][2]; const float* bS[2][2];
  const ushort_t* pWsS[2]; const float* bsS[2]; const float* qS[2];
  const float* session;
  ushort_t* hS[2]; float* wsumS[2];
};

__global__ __launch_bounds__(NT, 6)
void k_mega(MegaArgs a) {
  __shared__ int ids[32];
  __shared__ int nidx[640];
  __shared__ __align__(16) ushort_t xs[8320];   // item: [32][260]; S: [16][520]
  __shared__ float red[128];

  const int tid = threadIdx.x;
  const int l = tid & 63;
  const int w = tid >> 6;          // wave 0..3
  const int bid = blockIdx.x;
  const int lcol = l & 15;
  const int g8 = (l >> 4) << 3;
  const int nt0 = 2 * w;
  const int col0 = nt0 * 16 + lcol;
  const int col1 = col0 + 16;
  const _Float16 sch = (_Float16)(1.f / KK);
  const f16x2 scv = (f16x2){sch, sch};

  if (bid >= 128) {
    // =============== item path: one edge, 32 rows ===============
    const int t = bid - 128;
    const int e = t % 3;
    const int tile = t / 3;
    const int n0 = tile * 32;
    const int* nb = a.nbI[e];
    const uchar_t* emb = a.embI[e];
    const ushort_t* pW = a.pWI[e];
    const float* bias = a.bI[e];

    if (tid < 32) ids[tid] = a.item_idx[n0 + tid];
    __syncthreads();

    // nidx (32x20) + self rows (f32 -> fp16)
    for (int i = tid; i < 640; i += NT) {
      const int rr = i / KK, kk = i - rr * KK;
      nidx[i] = nb[(size_t)ids[rr] * KK + kk];
    }
    {
      const int r = tid >> 3, sl = tid & 7;   // 16 floats per thread
      const float* sp = a.item_f + ((size_t)ids[r] << 7) + sl * 16;
      const float4 v0 = *reinterpret_cast<const float4*>(sp);
      const float4 v1 = *reinterpret_cast<const float4*>(sp + 4);
      const float4 v2 = *reinterpret_cast<const float4*>(sp + 8);
      const float4 v3 = *reinterpret_cast<const float4*>(sp + 12);
      *reinterpret_cast<uint4*>(&xs[r * 260 + sl * 16]) = packf32x8(v0, v1);
      *reinterpret_cast<uint4*>(&xs[r * 260 + sl * 16 + 8]) = packf32x8(v2, v3);
    }
    __syncthreads();

    // gather-mean: 16B fp8 requests, thread = (row, 16-elem slice)
    {
      const int r = tid >> 3, sl = tid & 7;
      f16x2 acc[8];
#pragma unroll
      for (int i = 0; i < 8; ++i) acc[i] = (f16x2)0;
#pragma unroll
      for (int kb = 0; kb < KK; kb += 4) {
        uint4 u[4];
#pragma unroll
        for (int j = 0; j < 4; ++j)
          u[j] = *reinterpret_cast<const uint4*>(
              emb + ((size_t)nidx[r * KK + kb + j] << 7) + sl * 16);
#pragma unroll
        for (int j = 0; j < 4; ++j) f8acc16(acc, u[j]);
      }
#pragma unroll
      for (int i = 0; i < 8; ++i) acc[i] *= scv;
      UF P;
      P.v[0] = acc[0]; P.v[1] = acc[1]; P.v[2] = acc[2]; P.v[3] = acc[3];
      *reinterpret_cast<uint4*>(&xs[r * 260 + 128 + sl * 16]) = P.u4;
      P.v[0] = acc[4]; P.v[1] = acc[5]; P.v[2] = acc[6]; P.v[3] = acc[7];
      *reinterpret_cast<uint4*>(&xs[r * 260 + 128 + sl * 16 + 8]) = P.u4;
    }
    __syncthreads();

    // MFMA: h = relu(x @ W + b); 2 row-groups x 2 ntiles
    f32x4 a00, a01, a10, a11;
    {
      const float b0 = bias[col0], b1 = bias[col1];
      a00 = (f32x4){b0, b0, b0, b0}; a01 = (f32x4){b1, b1, b1, b1};
      a10 = a00; a11 = a01;
#pragma unroll
      for (int kt = 0; kt < 8; ++kt) {
        const int xcol = kt * 32 + g8;   // self 0..127, agg 128..255
        const f16x8 Aa = *reinterpret_cast<const f16x8*>((const void*)&xs[lcol * 260 + xcol]);
        const f16x8 Ab = *reinterpret_cast<const f16x8*>((const void*)&xs[(16 + lcol) * 260 + xcol]);
        const f16x8 B0 = *reinterpret_cast<const f16x8*>(
            (const void*)(pW + ((size_t)(kt * 8 + nt0) * 512) + l * 8));
        const f16x8 B1 = *reinterpret_cast<const f16x8*>(
            (const void*)(pW + ((size_t)(kt * 8 + nt0 + 1) * 512) + l * 8));
        a00 = __builtin_amdgcn_mfma_f32_16x16x32_f16(Aa, B0, a00, 0, 0, 0);
        a01 = __builtin_amdgcn_mfma_f32_16x16x32_f16(Aa, B1, a01, 0, 0, 0);
        a10 = __builtin_amdgcn_mfma_f32_16x16x32_f16(Ab, B0, a10, 0, 0, 0);
        a11 = __builtin_amdgcn_mfma_f32_16x16x32_f16(Ab, B1, a11, 0, 0, 0);
      }
#pragma unroll
      for (int j = 0; j < 4; ++j) {
        a00[j] = fmaxf(a00[j], 0.f); a01[j] = fmaxf(a01[j], 0.f);
        a10[j] = fmaxf(a10[j], 0.f); a11[j] = fmaxf(a11[j], 0.f);
      }
    }
    __syncthreads();  // agg-slot reads done before h overwrites it
    {
      const int rbase = (l >> 4) << 2;
#pragma unroll
      for (int j = 0; j < 4; ++j) {
        const int r0 = rbase + j, r1 = 16 + rbase + j;
        UH h00, h01, h10, h11;
        h00.h = __float2half_rn(a00[j]); h01.h = __float2half_rn(a01[j]);
        h10.h = __float2half_rn(a10[j]); h11.h = __float2half_rn(a11[j]);
        a.hI[(size_t)(n0 + r0) * 3 * DD + e * DD + col0] = h00.s;
        a.hI[(size_t)(n0 + r0) * 3 * DD + e * DD + col1] = h01.s;
        a.hI[(size_t)(n0 + r1) * 3 * DD + e * DD + col0] = h10.s;
        a.hI[(size_t)(n0 + r1) * 3 * DD + e * DD + col1] = h11.s;
        xs[r0 * 260 + 128 + col0] = h00.s;
        xs[r0 * 260 + 128 + col1] = h01.s;
        xs[r1 * 260 + 128 + col0] = h10.s;
        xs[r1 * 260 + 128 + col1] = h11.s;
      }
    }
    __syncthreads();  // h visible in LDS

    // score: t = h @ Ws + bs; w = sum tanh(t)*q
    {
      const float b0 = a.bsI[col0], b1 = a.bsI[col1];
      f32x4 s00 = (f32x4){b0, b0, b0, b0};
      f32x4 s01 = (f32x4){b1, b1, b1, b1};
      f32x4 s10 = s00, s11 = s01;
#pragma unroll
      for (int kt = 0; kt < 4; ++kt) {
        const f16x8 Aa = *reinterpret_cast<const f16x8*>(
            (const void*)&xs[lcol * 260 + 128 + kt * 32 + g8]);
        const f16x8 Ab = *reinterpret_cast<const f16x8*>(
            (const void*)&xs[(16 + lcol) * 260 + 128 + kt * 32 + g8]);
        const f16x8 B0 = *reinterpret_cast<const f16x8*>(
            (const void*)(a.pWsI + ((size_t)(kt * 8 + nt0) * 512) + l * 8));
        const f16x8 B1 = *reinterpret_cast<const f16x8*>(
            (const void*)(a.pWsI + ((size_t)(kt * 8 + nt0 + 1) * 512) + l * 8));
        s00 = __builtin_amdgcn_mfma_f32_16x16x32_f16(Aa, B0, s00, 0, 0, 0);
        s01 = __builtin_amdgcn_mfma_f32_16x16x32_f16(Aa, B1, s01, 0, 0, 0);
        s10 = __builtin_amdgcn_mfma_f32_16x16x32_f16(Ab, B0, s10, 0, 0, 0);
        s11 = __builtin_amdgcn_mfma_f32_16x16x32_f16(Ab, B1, s11, 0, 0, 0);
      }
      const float q0 = a.qI[col0], q1 = a.qI[col1];
      float p0[4], p1[4];
#pragma unroll
      for (int j = 0; j < 4; ++j) {
        p0[j] = fast_tanh(s00[j]) * q0 + fast_tanh(s01[j]) * q1;
        p1[j] = fast_tanh(s10[j]) * q0 + fast_tanh(s11[j]) * q1;
      }
#pragma unroll
      for (int off = 1; off < 16; off <<= 1) {
#pragma unroll
        for (int j = 0; j < 4; ++j) {
          p0[j] += __shfl_xor(p0[j], off, 64);
          p1[j] += __shfl_xor(p1[j], off, 64);
        }
      }
      if (lcol == 0) {
        const int rbase = (l >> 4) << 2;
#pragma unroll
        for (int j = 0; j < 4; ++j) {
          red[w * 32 + rbase + j] = p0[j];
          red[w * 32 + 16 + rbase + j] = p1[j];
        }
      }
    }
    __syncthreads();
    if (tid < 32) {
      float s = red[tid] + red[32 + tid] + red[64 + tid] + red[96 + tid];
#pragma unroll
      for (int off = 1; off < 32; off <<= 1) s += __shfl_xor(s, off, 64);
      if (tid == 0) atomicAdd(&a.wsumI[(tile & 63) * 4 + e], s);
    }
  } else {
    // =============== S path: 16 rows, 2 edges + session ===============
    const int g = bid >> 6;
    const int bl = bid & 63;
    const int n0 = bl * 16;
    const int gr = tid >> 4;      // 0..15
    const int gsl = tid & 15;     // 8-elem slice
    ushort_t* hd = a.hS[g];
    const ushort_t* pws = a.pWsS[g];
    const float* bss = a.bsS[g];
    const float* qp = a.qS[g];

    if (tid < 16) ids[tid] = a.sidx[g][n0 + tid];
    __syncthreads();
    for (int i = tid; i < 640; i += NT) {
      const int e2 = i / 320;
      const int r2 = (i - e2 * 320) / KK;
      const int k2 = i - e2 * 320 - r2 * KK;
      nidx[i] = a.nbS[g][e2][(size_t)ids[r2] * KK + k2];
    }
    {
      const float* sp = a.st_f[g] + ((size_t)ids[gr] << 7) + gsl * 8;
      const float4 v0 = *reinterpret_cast<const float4*>(sp);
      const float4 v1 = *reinterpret_cast<const float4*>(sp + 4);
      *reinterpret_cast<uint4*>(&xs[gr * 520 + gsl * 8]) = packf32x8(v0, v1);
    }
    __syncthreads();

    // gathers: both edges (8B requests), session passthrough
    {
      UF A0, A1;
#pragma unroll
      for (int i = 0; i < 4; ++i) { A0.v[i] = (f16x2)0; A1.v[i] = (f16x2)0; }
#pragma unroll
      for (int kb = 0; kb < KK; kb += 5) {
        uint2 u0[5], u1[5];
#pragma unroll
        for (int j = 0; j < 5; ++j)
          u0[j] = *reinterpret_cast<const uint2*>(
              a.embS[g][0] + ((size_t)nidx[gr * KK + kb + j] << 7) + gsl * 8);
#pragma unroll
        for (int j = 0; j < 5; ++j)
          u1[j] = *reinterpret_cast<const uint2*>(
              a.embS[g][1] + ((size_t)nidx[320 + gr * KK + kb + j] << 7) + gsl * 8);
#pragma unroll
        for (int j = 0; j < 5; ++j) { f8acc(A0.v, u0[j]); f8acc(A1.v, u1[j]); }
      }
#pragma unroll
      for (int i = 0; i < 4; ++i) { A0.v[i] *= scv; A1.v[i] *= scv; }
      *reinterpret_cast<uint4*>(&xs[gr * 520 + 128 + gsl * 8]) = A0.u4;
      *reinterpret_cast<uint4*>(&xs[gr * 520 + 256 + gsl * 8]) = A1.u4;
      const float* srow = a.session + (size_t)(n0 + gr) * DD + gsl * 8;
      const float4 v0 = *reinterpret_cast<const float4*>(srow);
      const float4 v1 = *reinterpret_cast<const float4*>(srow + 4);
      const uint4 o = packf32x8(v0, v1);
      *reinterpret_cast<uint4*>(&xs[gr * 520 + 384 + gsl * 8]) = o;
      *reinterpret_cast<uint4*>(hd + (size_t)(n0 + gr) * 3 * DD + 2 * DD + gsl * 8) = o;
    }
    __syncthreads();

#pragma unroll
    for (int e = 0; e < 3; ++e) {
      if (e < 2) {
        const ushort_t* pW = a.pWS[g][e];
        const float* bp = a.bS[g][e];
        f32x4 acc0, acc1;
        {
          const float b0 = bp[col0], b1 = bp[col1];
          acc0 = (f32x4){b0, b0, b0, b0};
          acc1 = (f32x4){b1, b1, b1, b1};
#pragma unroll
          for (int kt = 0; kt < 8; ++kt) {
            const int xcol = (kt < 4) ? (kt * 32 + g8) : (e * DD + kt * 32 + g8);
            const f16x8 Aa = *reinterpret_cast<const f16x8*>((const void*)&xs[lcol * 520 + xcol]);
            const f16x8 B0 = *reinterpret_cast<const f16x8*>(
                (const void*)(pW + ((size_t)(kt * 8 + nt0) * 512) + l * 8));
            const f16x8 B1 = *reinterpret_cast<const f16x8*>(
                (const void*)(pW + ((size_t)(kt * 8 + nt0 + 1) * 512) + l * 8));
            acc0 = __builtin_amdgcn_mfma_f32_16x16x32_f16(Aa, B0, acc0, 0, 0, 0);
            acc1 = __builtin_amdgcn_mfma_f32_16x16x32_f16(Aa, B1, acc1, 0, 0, 0);
          }
#pragma unroll
          for (int j = 0; j < 4; ++j) {
            acc0[j] = fmaxf(acc0[j], 0.f);
            acc1[j] = fmaxf(acc1[j], 0.f);
          }
        }
        __syncthreads();
        {
          const int rbase = (l >> 4) << 2;
#pragma unroll
          for (int j = 0; j < 4; ++j) {
            const int r0 = rbase + j;
            UH h0, h1;
            h0.h = __float2half_rn(acc0[j]);
            h1.h = __float2half_rn(acc1[j]);
            hd[(size_t)(n0 + r0) * 3 * DD + e * DD + col0] = h0.s;
            hd[(size_t)(n0 + r0) * 3 * DD + e * DD + col1] = h1.s;
            xs[r0 * 520 + (e + 1) * DD + col0] = h0.s;
            xs[r0 * 520 + (e + 1) * DD + col1] = h1.s;
          }
        }
        __syncthreads();
      }
      // score on slot e+1
      {
        const float b0 = bss[col0], b1 = bss[col1];
        f32x4 s0 = (f32x4){b0, b0, b0, b0};
        f32x4 s1 = (f32x4){b1, b1, b1, b1};
#pragma unroll
        for (int kt = 0; kt < 4; ++kt) {
          const f16x8 Aa = *reinterpret_cast<const f16x8*>(
              (const void*)&xs[lcol * 520 + (e + 1) * DD + kt * 32 + g8]);
          const f16x8 B0 = *reinterpret_cast<const f16x8*>(
              (const void*)(pws + ((size_t)(kt * 8 + nt0) * 512) + l * 8));
          const f16x8 B1 = *reinterpret_cast<const f16x8*>(
              (const void*)(pws + ((size_t)(kt * 8 + nt0 + 1) * 512) + l * 8));
          s0 = __builtin_amdgcn_mfma_f32_16x16x32_f16(Aa, B0, s0, 0, 0, 0);
          s1 = __builtin_amdgcn_mfma_f32_16x16x32_f16(Aa, B1, s1, 0, 0, 0);
        }
        const float q0 = qp[col0], q1 = qp[col1];
        float p0[4];
#pragma unroll
        for (int j = 0; j < 4; ++j)
          p0[j] = fast_tanh(s0[j]) * q0 + fast_tanh(s1[j]) * q1;
#pragma unroll
        for (int off = 1; off < 16; off <<= 1) {
#pragma unroll
          for (int j = 0; j < 4; ++j) p0[j] += __shfl_xor(p0[j], off, 64);
        }
        if (lcol == 0) {
          const int rbase = (l >> 4) << 2;
#pragma unroll
          for (int j = 0; j < 4; ++j) red[w * 32 + rbase + j] = p0[j];
        }
      }
      __syncthreads();
      if (tid < 16) {
        float s = red[tid] + red[32 + tid] + red[64 + tid] + red[96 + tid];
#pragma unroll
        for (int off = 1; off < 16; off <<= 1) s += __shfl_xor(s, off, 64);
        if (tid == 0) atomicAdd(&a.wsumS[g][(bl & 63) * 4 + e], s);
      }
      __syncthreads();
    }
  }
}

// ---------------------------------------------------------------------------
__global__ void k_beta(const float* __restrict__ wsum, float* __restrict__ beta) {
  if (threadIdx.x == 0 && blockIdx.x == 0) {
    const float invN[3] = {1.f / 51200.f, 1.f / 1024.f, 1.f / 1024.f};
    for (int g = 0; g < 3; ++g) {
      float s0 = 0.f, s1 = 0.f, s2 = 0.f;
      for (int bkt = 0; bkt < 64; ++bkt) {
        s0 += wsum[g * 256 + bkt * 4 + 0];
        s1 += wsum[g * 256 + bkt * 4 + 1];
        s2 += wsum[g * 256 + bkt * 4 + 2];
      }
      s0 *= invN[g]; s1 *= invN[g]; s2 *= invN[g];
      const float mx = fmaxf(s0, fmaxf(s1, s2));
      const float e0 = expf(s0 - mx), e1 = expf(s1 - mx), e2 = expf(s2 - mx);
      const float inv = 1.f / (e0 + e1 + e2);
      beta[g * 4 + 0] = e0 * inv;
      beta[g * 4 + 1] = e1 * inv;
      beta[g * 4 + 2] = e2 * inv;
    }
  }
}

// out[row, c0..c0+3] = sum_m beta[g][m] * h[row,m,c0..c0+3]
__global__ __launch_bounds__(256)
void k_out(const ushort_t* __restrict__ h, const float* __restrict__ beta,
           float* __restrict__ out) {
  const int t = blockIdx.x * blockDim.x + threadIdx.x;  // 53248*32
  const int row = t >> 5;
  const int c0 = (t & 31) * 4;
  const int g = (row < 51200) ? 0 : ((row < 52224) ? 1 : 2);
  const float* bt = beta + g * 4;
  const size_t base = (size_t)row * 3 * DD + c0;
  const ushort4 ha = *reinterpret_cast<const ushort4*>(&h[base]);
  const ushort4 hb = *reinterpret_cast<const ushort4*>(&h[base + DD]);
  const ushort4 hc = *reinterpret_cast<const ushort4*>(&h[base + 2 * DD]);
  UH u;
  float4 o;
  float va, vb, vc;
  u.s = ha.x; va = __half2float(u.h); u.s = hb.x; vb = __half2float(u.h);
  u.s = hc.x; vc = __half2float(u.h);
  o.x = bt[0] * va + bt[1] * vb + bt[2] * vc;
  u.s = ha.y; va = __half2float(u.h); u.s = hb.y; vb = __half2float(u.h);
  u.s = hc.y; vc = __half2float(u.h);
  o.y = bt[0] * va + bt[1] * vb + bt[2] * vc;
  u.s = ha.z; va = __half2float(u.h); u.s = hb.z; vb = __half2float(u.h);
  u.s = hc.z; vc = __half2float(u.h);
  o.z = bt[0] * va + bt[1] * vb + bt[2] * vc;
  u.s = ha.w; va = __half2float(u.h); u.s = hb.w; vb = __half2float(u.h);
  u.s = hc.w; vc = __half2float(u.h);
  o.w = bt[0] * va + bt[1] * vb + bt[2] * vc;
  *reinterpret_cast<float4*>(&out[(size_t)row * DD + c0]) = o;
}

// ---------------------------------------------------------------------------

extern "C" void kernel_launch(void* const* d_in, const int* in_sizes, int n_in,
                              void* d_out, int out_size, void* d_ws, size_t ws_size,
                              hipStream_t stream) {
  const int*   item     = (const int*)  d_in[0];
  const int*   locs     = (const int*)  d_in[1];
  const int*   times    = (const int*)  d_in[2];
  const float* session  = (const float*)d_in[3];
  const float* loc_emb  = (const float*)d_in[4];
  const float* time_emb = (const float*)d_in[5];
  const float* item_emb = (const float*)d_in[6];
  const int* nb_IL = (const int*)d_in[7];
  const int* nb_TL = (const int*)d_in[8];
  const int* nb_IT = (const int*)d_in[9];
  const int* nb_LT = (const int*)d_in[10];
  const int* nb_II = (const int*)d_in[11];
  const int* nb_LI = (const int*)d_in[12];
  const int* nb_TI = (const int*)d_in[13];
  const float* W_IL = (const float*)d_in[14]; const float* b_IL = (const float*)d_in[15];
  const float* W_TL = (const float*)d_in[16]; const float* b_TL = (const float*)d_in[17];
  const float* W_IT = (const float*)d_in[18]; const float* b_IT = (const float*)d_in[19];
  const float* W_LT = (const float*)d_in[20]; const float* b_LT = (const float*)d_in[21];
  const float* W_II = (const float*)d_in[22]; const float* b_II = (const float*)d_in[23];
  const float* W_LI = (const float*)d_in[24]; const float* b_LI = (const float*)d_in[25];
  const float* W_TI = (const float*)d_in[26]; const float* b_TI = (const float*)d_in[27];
  const float* Ws_l = (const float*)d_in[28]; const float* bs_l = (const float*)d_in[29];
  const float* q_l  = (const float*)d_in[30];
  const float* Ws_t = (const float*)d_in[31]; const float* bs_t = (const float*)d_in[32];
  const float* q_t  = (const float*)d_in[33];
  const float* Ws_i = (const float*)d_in[34]; const float* bs_i = (const float*)d_in[35];
  const float* q_i  = (const float*)d_in[36];

  float* outp = (float*)d_out;

  // ws: wsum/beta(16K) | packed W(544K) | hbuf fp16(40.9M) | fp8 tables(14.3M)
  char* wsb = (char*)d_ws;
  float* wsum  = (float*)wsb;
  float* betap = (float*)wsb + 1024;
  ushort_t* pk = (ushort_t*)(wsb + 16384);
  ushort_t* pk_II = pk;
  ushort_t* pk_TI = pk_II + 32768;
  ushort_t* pk_LI = pk_TI + 32768;
  ushort_t* pk_IL = pk_LI + 32768;
  ushort_t* pk_TL = pk_IL + 32768;
  ushort_t* pk_IT = pk_TL + 32768;
  ushort_t* pk_LT = pk_IT + 32768;
  ushort_t* pk_Wi = pk_LT + 32768;
  ushort_t* pk_Wl = pk_Wi + 16384;
  ushort_t* pk_Wt = pk_Wl + 16384;
  ushort_t* hbuf  = pk_Wt + 16384;
  uchar_t* item_8 = (uchar_t*)(hbuf + (size_t)53248 * 3 * DD);
  uchar_t* loc_8  = item_8 + (size_t)100000 * DD;
  uchar_t* time_8 = loc_8 + (size_t)10000 * DD;

  (void)hipMemsetAsync(d_ws, 0, 16384, stream);

  CvtArgs ca;
  ca.item = item_emb; ca.loc = loc_emb; ca.timet = time_emb;
  ca.dst8 = item_8;
  k_cvt3<<<dim3(7000), dim3(256), 0, stream>>>(ca);

  PackArgs pa;
  pa.src[0] = W_II; pa.src[1] = W_TI; pa.src[2] = W_LI;
  pa.src[3] = W_IL; pa.src[4] = W_TL; pa.src[5] = W_IT; pa.src[6] = W_LT;
  pa.src[7] = Ws_i; pa.src[8] = Ws_l; pa.src[9] = Ws_t;
  pa.dst = pk;
  k_pack10<<<dim3(136), dim3(256), 0, stream>>>(pa);

  ushort_t* h_items = hbuf;
  ushort_t* h_locs  = hbuf + (size_t)51200 * 3 * DD;
  ushort_t* h_times = hbuf + (size_t)52224 * 3 * DD;

  MegaArgs ma;
  ma.item_idx = item; ma.item_f = item_emb;
  ma.nbI[0] = nb_II; ma.nbI[1] = nb_TI; ma.nbI[2] = nb_LI;
  ma.embI[0] = item_8; ma.embI[1] = time_8; ma.embI[2] = loc_8;
  ma.pWI[0] = pk_II; ma.pWI[1] = pk_TI; ma.pWI[2] = pk_LI;
  ma.bI[0] = b_II; ma.bI[1] = b_TI; ma.bI[2] = b_LI;
  ma.pWsI = pk_Wi; ma.bsI = bs_i; ma.qI = q_i;
  ma.hI = h_items; ma.wsumI = wsum + 0;
  ma.sidx[0] = locs;  ma.sidx[1] = times;
  ma.st_f[0] = loc_emb; ma.st_f[1] = time_emb;
  ma.nbS[0][0] = nb_IL; ma.nbS[0][1] = nb_TL;
  ma.nbS[1][0] = nb_IT; ma.nbS[1][1] = nb_LT;
  ma.embS[0][0] = item_8; ma.embS[0][1] = time_8;
  ma.embS[1][0] = item_8; ma.embS[1][1] = loc_8;
  ma.pWS[0][0] = pk_IL; ma.pWS[0][1] = pk_TL;
  ma.pWS[1][0] = pk_IT; ma.pWS[1][1] = pk_LT;
  ma.bS[0][0] = b_IL; ma.bS[0][1] = b_TL;
  ma.bS[1][0] = b_IT; ma.bS[1][1] = b_LT;
  ma.pWsS[0] = pk_Wl; ma.pWsS[1] = pk_Wt;
  ma.bsS[0] = bs_l; ma.bsS[1] = bs_t;
  ma.qS[0] = q_l; ma.qS[1] = q_t;
  ma.session = session;
  ma.hS[0] = h_locs; ma.hS[1] = h_times;
  ma.wsumS[0] = wsum + 256; ma.wsumS[1] = wsum + 512;
  k_mega<<<dim3(128 + 4800), dim3(NT), 0, stream>>>(ma);

  k_beta<<<dim3(1), dim3(64), 0, stream>>>(wsum, betap);
  k_out<<<dim3((53248 * 32) / 256), dim3(256), 0, stream>>>(hbuf, betap, outp);
}

// Round 17
// 117.700 us; speedup vs baseline: 1.0554x; 1.0554x over previous
//
#include <hip/hip_runtime.h>
#include <hip/hip_fp16.h>

#define DD 128
#define KK 20
#define TRR 32
#define NT 512

typedef unsigned int uint_t;
typedef unsigned short ushort_t;
typedef unsigned char uchar_t;
typedef _Float16 f16x8 __attribute__((ext_vector_type(8)));
typedef _Float16 f16x2 __attribute__((ext_vector_type(2)));
typedef __fp16 h16x2 __attribute__((ext_vector_type(2)));
typedef float f32x4 __attribute__((ext_vector_type(4)));
typedef float f32x2 __attribute__((ext_vector_type(2)));

union UH { __half h; ushort_t s; };
union UF { f16x2 v[4]; uint4 u4; };
union CV { h16x2 a; f16x2 b; };

#if __has_builtin(__builtin_amdgcn_cvt_scalef32_pk_f16_fp8)
#define HAVE_SCALEF32 1
#endif

__device__ __forceinline__ float fast_tanh(float x) {
  const float e = __expf(2.f * x);
  return 1.f - 2.f / (e + 1.f);
}

// convert 8 fp8 (uint2) -> 4 packed f16x2
__device__ __forceinline__ UF f8cvt(const uint2 v) {
  UF r;
#ifdef HAVE_SCALEF32
  r.v[0] = __builtin_amdgcn_cvt_scalef32_pk_f16_fp8(v.x, 1.0f, false);
  r.v[1] = __builtin_amdgcn_cvt_scalef32_pk_f16_fp8(v.x, 1.0f, true);
  r.v[2] = __builtin_amdgcn_cvt_scalef32_pk_f16_fp8(v.y, 1.0f, false);
  r.v[3] = __builtin_amdgcn_cvt_scalef32_pk_f16_fp8(v.y, 1.0f, true);
#else
  f32x2 p;
  CV c;
  p = __builtin_amdgcn_cvt_pk_f32_fp8(v.x, false);
  c.a = __builtin_amdgcn_cvt_pkrtz(p[0], p[1]); r.v[0] = c.b;
  p = __builtin_amdgcn_cvt_pk_f32_fp8(v.x, true);
  c.a = __builtin_amdgcn_cvt_pkrtz(p[0], p[1]); r.v[1] = c.b;
  p = __builtin_amdgcn_cvt_pk_f32_fp8(v.y, false);
  c.a = __builtin_amdgcn_cvt_pkrtz(p[0], p[1]); r.v[2] = c.b;
  p = __builtin_amdgcn_cvt_pk_f32_fp8(v.y, true);
  c.a = __builtin_amdgcn_cvt_pkrtz(p[0], p[1]); r.v[3] = c.b;
#endif
  return r;
}

__device__ __forceinline__ void f8acc(f16x2* a, const uint2 v) {
  const UF r = f8cvt(v);
  a[0] += r.v[0]; a[1] += r.v[1]; a[2] += r.v[2]; a[3] += r.v[3];
}

// accumulate 16 fp8 (uint4) into 8 packed f16x2
__device__ __forceinline__ void f8acc16(f16x2* a, const uint4 v) {
  uint2 lo; lo.x = v.x; lo.y = v.y;
  uint2 hi; hi.x = v.z; hi.y = v.w;
  f8acc(a, lo);
  f8acc(a + 4, hi);
}

__device__ __forceinline__ uint4 packf32x8(const float4 v0, const float4 v1) {
  UH h0, h1, h2, h3, h4, h5, h6, h7;
  h0.h = __float2half_rn(v0.x); h1.h = __float2half_rn(v0.y);
  h2.h = __float2half_rn(v0.z); h3.h = __float2half_rn(v0.w);
  h4.h = __float2half_rn(v1.x); h5.h = __float2half_rn(v1.y);
  h6.h = __float2half_rn(v1.z); h7.h = __float2half_rn(v1.w);
  uint4 o;
  o.x = (uint_t)h0.s | ((uint_t)h1.s << 16);
  o.y = (uint_t)h2.s | ((uint_t)h3.s << 16);
  o.z = (uint_t)h4.s | ((uint_t)h5.s << 16);
  o.w = (uint_t)h6.s | ((uint_t)h7.s << 16);
  return o;
}

// ---------------------------------------------------------------------------
// k_prep: fused table conversion (blocks 0..6999) + weight packing (7000..7135)
// ---------------------------------------------------------------------------
struct PrepArgs {
  const float* item; const float* loc; const float* timet;
  uchar_t* dst8;
  const float* wsrc[10];
  ushort_t* wdst;
};

__global__ __launch_bounds__(256)
void k_prep(PrepArgs a) {
  const int b = blockIdx.x, tid = threadIdx.x;
  if (b < 7000) {
    // f32 tables -> fp8 region, 8 elems/thread
    const int t = b * 256 + tid;  // 1,792,000 total
    const float* src;
    if (t < 1600000) src = a.item + (size_t)t * 8;
    else if (t < 1760000) src = a.loc + ((size_t)t - 1600000) * 8;
    else src = a.timet + ((size_t)t - 1760000) * 8;
    const float4* ip = reinterpret_cast<const float4*>(src);
    const float4 x = ip[0], y = ip[1];
    uint_t p0 = __builtin_amdgcn_cvt_pk_fp8_f32(x.x, x.y, 0u, false);
    p0 = __builtin_amdgcn_cvt_pk_fp8_f32(x.z, x.w, p0, true);
    uint_t p1 = __builtin_amdgcn_cvt_pk_fp8_f32(y.x, y.y, 0u, false);
    p1 = __builtin_amdgcn_cvt_pk_fp8_f32(y.z, y.w, p1, true);
    uint2 q; q.x = p0; q.y = p1;
    reinterpret_cast<uint2*>(a.dst8)[t] = q;
  } else {
    // weight pack: W[K][128] f32 -> MFMA B-fragment order fp16.
    // Fragment (kt,nt): lane l, reg j <- W[kt*32+(l>>4)*8+j][nt*16+(l&15)]
    const int pb = b - 7000;
    int job, tin;
    size_t doff;
    if (pb < 112) {
      job = pb >> 4; tin = ((pb & 15) << 8) | tid;
      doff = (size_t)job * 32768;
    } else {
      job = 7 + ((pb - 112) >> 3); tin = (((pb - 112) & 7) << 8) | tid;
      doff = 7ull * 32768 + (size_t)(job - 7) * 16384;
    }
    const float* W = a.wsrc[job];
    const int l = tin & 63;
    const int ktnt = tin >> 6;
    const int nt = ktnt & 7;
    const int kt = ktnt >> 3;
    const int col = nt * 16 + (l & 15);
    const int kb = kt * 32 + ((l >> 4) << 3);
    UH h[8];
#pragma unroll
    for (int j = 0; j < 8; ++j) h[j].h = __float2half_rn(W[(size_t)(kb + j) * DD + col]);
    uint4 o;
    o.x = (uint_t)h[0].s | ((uint_t)h[1].s << 16);
    o.y = (uint_t)h[2].s | ((uint_t)h[3].s << 16);
    o.z = (uint_t)h[4].s | ((uint_t)h[5].s << 16);
    o.w = (uint_t)h[6].s | ((uint_t)h[7].s << 16);
    *reinterpret_cast<uint4*>(a.wdst + doff + (size_t)ktnt * 512 + l * 8) = o;
  }
}

// ---------------------------------------------------------------------------
// k_mega: 512 threads = 8 waves, 32 rows/block; wave w owns ntile w.
// R15 structure (best measured: 86us, no spill). Item gathers use 16B fp8
// requests (8 threads/row); self rows read from original f32 tables.
// blocks 0..63: locs/times; 64..: items.
// ---------------------------------------------------------------------------
struct MegaArgs {
  // items
  const int* item_idx; const float* item_f;
  const int* nbI[3]; const uchar_t* embI[3]; const ushort_t* pWI[3]; const float* bI[3];
  const ushort_t* pWsI; const float* bsI; const float* qI;
  ushort_t* hI; float* wsumI;
  // locs (g=0) / times (g=1)
  const int* sidx[2]; const float* st_f[2];
  const int* nbS[2][2]; const uchar_t* embS[2][2];
  const ushort_t* pWS[2][2]; const float* bS[2][2];
  const ushort_t* pWsS[2]; const float* bsS[2]; const float* qS[2];
  const float* session;
  ushort_t* hS[2]; float* wsumS[2];
};

__global__ __launch_bounds__(NT, 6)
void k_mega(MegaArgs a) {
  __shared__ int ids[TRR];
  __shared__ int nidx[3][TRR][KK];
  __shared__ __align__(16) ushort_t xs[TRR][4 * DD + 8];   // 520: self|s1|s2|s3
  __shared__ float red[8][TRR];

  const int tid = threadIdx.x;
  const int l = tid & 63;
  const int w = tid >> 6;         // wave 0..7 -> ntile
  const int bid = blockIdx.x;

  const bool isS = bid < 64;
  const int g = isS ? (bid >> 5) : 0;
  const int bl = isS ? (bid & 31) : (bid - 64);
  const int n0 = bl * TRR;

  const int* sidx;
  const float* selfF;
  const int* nb_[3];
  const uchar_t* emb_[3];
  const ushort_t* pW_[3];
  const float* bias_[3];
  const ushort_t* pws; const float* bss; const float* qp;
  ushort_t* hd; float* wbase;
  if (!isS) {
    sidx = a.item_idx; selfF = a.item_f;
    nb_[0] = a.nbI[0]; nb_[1] = a.nbI[1]; nb_[2] = a.nbI[2];
    emb_[0] = a.embI[0]; emb_[1] = a.embI[1]; emb_[2] = a.embI[2];
    pW_[0] = a.pWI[0]; pW_[1] = a.pWI[1]; pW_[2] = a.pWI[2];
    bias_[0] = a.bI[0]; bias_[1] = a.bI[1]; bias_[2] = a.bI[2];
    pws = a.pWsI; bss = a.bsI; qp = a.qI;
    hd = a.hI; wbase = a.wsumI;
  } else if (g == 0) {
    sidx = a.sidx[0]; selfF = a.st_f[0];
    nb_[0] = a.nbS[0][0]; nb_[1] = a.nbS[0][1]; nb_[2] = nullptr;
    emb_[0] = a.embS[0][0]; emb_[1] = a.embS[0][1]; emb_[2] = nullptr;
    pW_[0] = a.pWS[0][0]; pW_[1] = a.pWS[0][1]; pW_[2] = nullptr;
    bias_[0] = a.bS[0][0]; bias_[1] = a.bS[0][1]; bias_[2] = nullptr;
    pws = a.pWsS[0]; bss = a.bsS[0]; qp = a.qS[0];
    hd = a.hS[0]; wbase = a.wsumS[0];
  } else {
    sidx = a.sidx[1]; selfF = a.st_f[1];
    nb_[0] = a.nbS[1][0]; nb_[1] = a.nbS[1][1]; nb_[2] = nullptr;
    emb_[0] = a.embS[1][0]; emb_[1] = a.embS[1][1]; emb_[2] = nullptr;
    pW_[0] = a.pWS[1][0]; pW_[1] = a.pWS[1][1]; pW_[2] = nullptr;
    bias_[0] = a.bS[1][0]; bias_[1] = a.bS[1][1]; bias_[2] = nullptr;
    pws = a.pWsS[1]; bss = a.bsS[1]; qp = a.qS[1];
    hd = a.hS[1]; wbase = a.wsumS[1];
  }

  if (tid < TRR) ids[tid] = sidx[n0 + tid];
  __syncthreads();

  const int gr = tid >> 4;        // row 0..31 (self staging)
  const int gsl = tid & 15;       // 8-float slice

  // stage neighbor index lists (edge-major)
#pragma unroll
  for (int e = 0; e < 3; ++e) {
    if (nb_[e]) {
      for (int t = tid; t < TRR * KK; t += NT) {
        const int rr = t / KK, kk = t - rr * KK;
        nidx[e][rr][kk] = nb_[e][(size_t)ids[rr] * KK + kk];
      }
    }
  }
  // self slice from the original f32 table (8 floats -> 8 halfs)
  {
    const float* sp = selfF + ((size_t)ids[gr] << 7) + gsl * 8;
    const float4 v0 = *reinterpret_cast<const float4*>(sp);
    const float4 v1 = *reinterpret_cast<const float4*>(sp + 4);
    *reinterpret_cast<uint4*>(&xs[gr][gsl * 8]) = packf32x8(v0, v1);
  }
  __syncthreads();

  const _Float16 sch = (_Float16)(1.f / KK);
  const f16x2 scv = (f16x2){sch, sch};
  const int lcol = l & 15;
  const int g8 = (l >> 4) << 3;
  const int col0 = w * 16 + lcol;

  // ---- gathers ----
  if (!isS) {
    // 16B-request gather: threads 0..255, thread = (row, 16-elem slice)
    if (tid < 256) {
      const int r = tid >> 3;
      const int sl = tid & 7;          // 16 fp8 elems = 16 bytes
      f16x2 a0[8], a1[8], a2[8];
#pragma unroll
      for (int i = 0; i < 8; ++i) { a0[i] = (f16x2)0; a1[i] = (f16x2)0; a2[i] = (f16x2)0; }
#pragma unroll
      for (int kb = 0; kb < KK; kb += 2) {
        uint4 u0[2], u1[2], u2[2];
#pragma unroll
        for (int j = 0; j < 2; ++j)
          u0[j] = *reinterpret_cast<const uint4*>(
              emb_[0] + ((size_t)nidx[0][r][kb + j] << 7) + sl * 16);
#pragma unroll
        for (int j = 0; j < 2; ++j)
          u1[j] = *reinterpret_cast<const uint4*>(
              emb_[1] + ((size_t)nidx[1][r][kb + j] << 7) + sl * 16);
#pragma unroll
        for (int j = 0; j < 2; ++j)
          u2[j] = *reinterpret_cast<const uint4*>(
              emb_[2] + ((size_t)nidx[2][r][kb + j] << 7) + sl * 16);
#pragma unroll
        for (int j = 0; j < 2; ++j) {
          f8acc16(a0, u0[j]); f8acc16(a1, u1[j]); f8acc16(a2, u2[j]);
        }
      }
#pragma unroll
      for (int i = 0; i < 8; ++i) { a0[i] *= scv; a1[i] *= scv; a2[i] *= scv; }
      UF P;
      P.v[0] = a0[0]; P.v[1] = a0[1]; P.v[2] = a0[2]; P.v[3] = a0[3];
      *reinterpret_cast<uint4*>(&xs[r][1 * DD + sl * 16]) = P.u4;
      P.v[0] = a0[4]; P.v[1] = a0[5]; P.v[2] = a0[6]; P.v[3] = a0[7];
      *reinterpret_cast<uint4*>(&xs[r][1 * DD + sl * 16 + 8]) = P.u4;
      P.v[0] = a1[0]; P.v[1] = a1[1]; P.v[2] = a1[2]; P.v[3] = a1[3];
      *reinterpret_cast<uint4*>(&xs[r][2 * DD + sl * 16]) = P.u4;
      P.v[0] = a1[4]; P.v[1] = a1[5]; P.v[2] = a1[6]; P.v[3] = a1[7];
      *reinterpret_cast<uint4*>(&xs[r][2 * DD + sl * 16 + 8]) = P.u4;
      P.v[0] = a2[0]; P.v[1] = a2[1]; P.v[2] = a2[2]; P.v[3] = a2[3];
      *reinterpret_cast<uint4*>(&xs[r][3 * DD + sl * 16]) = P.u4;
      P.v[0] = a2[4]; P.v[1] = a2[5]; P.v[2] = a2[6]; P.v[3] = a2[7];
      *reinterpret_cast<uint4*>(&xs[r][3 * DD + sl * 16 + 8]) = P.u4;
    }
  } else {
    // S path: 8B gathers (64 blocks total, not hot)
    UF A0, A1;
#pragma unroll
    for (int i = 0; i < 4; ++i) { A0.v[i] = (f16x2)0; A1.v[i] = (f16x2)0; }
#pragma unroll
    for (int kb = 0; kb < KK; kb += 5) {
      uint2 u0[5], u1[5];
#pragma unroll
      for (int j = 0; j < 5; ++j)
        u0[j] = *reinterpret_cast<const uint2*>(
            emb_[0] + ((size_t)nidx[0][gr][kb + j] << 7) + gsl * 8);
#pragma unroll
      for (int j = 0; j < 5; ++j)
        u1[j] = *reinterpret_cast<const uint2*>(
            emb_[1] + ((size_t)nidx[1][gr][kb + j] << 7) + gsl * 8);
#pragma unroll
      for (int j = 0; j < 5; ++j) { f8acc(A0.v, u0[j]); f8acc(A1.v, u1[j]); }
    }
#pragma unroll
    for (int i = 0; i < 4; ++i) { A0.v[i] *= scv; A1.v[i] *= scv; }
    *reinterpret_cast<uint4*>(&xs[gr][1 * DD + gsl * 8]) = A0.u4;
    *reinterpret_cast<uint4*>(&xs[gr][2 * DD + gsl * 8]) = A1.u4;
    // session -> slot 3 (fp16) + hbuf m=2
    const float* srow = a.session + (size_t)(n0 + gr) * DD + gsl * 8;
    const float4 v0 = *reinterpret_cast<const float4*>(srow);
    const float4 v1 = *reinterpret_cast<const float4*>(srow + 4);
    const uint4 o = packf32x8(v0, v1);
    *reinterpret_cast<uint4*>(&xs[gr][3 * DD + gsl * 8]) = o;
    *reinterpret_cast<uint4*>(hd + (size_t)(n0 + gr) * 3 * DD + 2 * DD + gsl * 8) = o;
  }
  __syncthreads();

  // ---- per-edge MFMA + score. wave w -> ntile w; 2 row-groups share B ----
#pragma unroll
  for (int e = 0; e < 3; ++e) {
    const bool full = (!isS) || (e < 2);
    if (full) {
      const ushort_t* pWp = pW_[e];
      const float* bp = bias_[e];
      f32x4 acc0, acc1;   // rows 0-15 / rows 16-31
      {
        const float b0 = bp[col0];
        acc0 = (f32x4){b0, b0, b0, b0};
        acc1 = acc0;
#pragma unroll
        for (int kt = 0; kt < 8; ++kt) {
          const int xcol = (kt < 4) ? (kt * 32 + g8) : (e * DD + kt * 32 + g8);
          const f16x8 Aa = *reinterpret_cast<const f16x8*>((const void*)&xs[lcol][xcol]);
          const f16x8 Ab = *reinterpret_cast<const f16x8*>((const void*)&xs[16 + lcol][xcol]);
          const f16x8 B = *reinterpret_cast<const f16x8*>(
              (const void*)(pWp + ((size_t)(kt * 8 + w) * 512) + l * 8));
          acc0 = __builtin_amdgcn_mfma_f32_16x16x32_f16(Aa, B, acc0, 0, 0, 0);
          acc1 = __builtin_amdgcn_mfma_f32_16x16x32_f16(Ab, B, acc1, 0, 0, 0);
        }
#pragma unroll
        for (int j = 0; j < 4; ++j) {
          acc0[j] = fmaxf(acc0[j], 0.f);
          acc1[j] = fmaxf(acc1[j], 0.f);
        }
      }
      __syncthreads();  // all A-reads of slot e+1 done before overwrite
      {
        const int rbase = (l >> 4) << 2;
#pragma unroll
        for (int j = 0; j < 4; ++j) {
          const int r0 = rbase + j, r1 = 16 + rbase + j;
          UH h0, h1;
          h0.h = __float2half_rn(acc0[j]);
          h1.h = __float2half_rn(acc1[j]);
          hd[(size_t)(n0 + r0) * 3 * DD + e * DD + col0] = h0.s;
          hd[(size_t)(n0 + r1) * 3 * DD + e * DD + col0] = h1.s;
          xs[r0][(e + 1) * DD + col0] = h0.s;
          xs[r1][(e + 1) * DD + col0] = h1.s;
        }
      }
      __syncthreads();  // h visible in LDS
    }
    // score: t = h @ Ws + bs; w-score = sum_cols tanh(t)*q
    {
      const float b0 = bss[col0];
      f32x4 s0 = (f32x4){b0, b0, b0, b0};
      f32x4 s1 = s0;
#pragma unroll
      for (int kt = 0; kt < 4; ++kt) {
        const f16x8 Aa = *reinterpret_cast<const f16x8*>(
            (const void*)&xs[lcol][(e + 1) * DD + kt * 32 + g8]);
        const f16x8 Ab = *reinterpret_cast<const f16x8*>(
            (const void*)&xs[16 + lcol][(e + 1) * DD + kt * 32 + g8]);
        const f16x8 B = *reinterpret_cast<const f16x8*>(
            (const void*)(pws + ((size_t)(kt * 8 + w) * 512) + l * 8));
        s0 = __builtin_amdgcn_mfma_f32_16x16x32_f16(Aa, B, s0, 0, 0, 0);
        s1 = __builtin_amdgcn_mfma_f32_16x16x32_f16(Ab, B, s1, 0, 0, 0);
      }
      const float q0 = qp[col0];
      float p0[4], p1[4];
#pragma unroll
      for (int j = 0; j < 4; ++j) {
        p0[j] = fast_tanh(s0[j]) * q0;
        p1[j] = fast_tanh(s1[j]) * q0;
      }
#pragma unroll
      for (int off = 1; off < 16; off <<= 1) {
#pragma unroll
        for (int j = 0; j < 4; ++j) {
          p0[j] += __shfl_xor(p0[j], off, 64);
          p1[j] += __shfl_xor(p1[j], off, 64);
        }
      }
      if (lcol == 0) {
        const int rbase = (l >> 4) << 2;
#pragma unroll
        for (int j = 0; j < 4; ++j) {
          red[w][rbase + j] = p0[j];
          red[w][16 + rbase + j] = p1[j];
        }
      }
    }
    __syncthreads();
    if (tid < TRR) {
      float s = 0.f;
#pragma unroll
      for (int ww = 0; ww < 8; ++ww) s += red[ww][tid];
#pragma unroll
      for (int off = 1; off < 32; off <<= 1) s += __shfl_xor(s, off, 64);
      if (tid == 0) atomicAdd(&wbase[(bl & 63) * 4 + e], s);
    }
    __syncthreads();
  }
}

// ---------------------------------------------------------------------------
// k_out: beta (softmax over wsum means) computed inline per block, then
// out[row, c0..3] = sum_m beta[g][m] * h[row,m,c0..3]
// ---------------------------------------------------------------------------
__global__ __launch_bounds__(256)
void k_out(const ushort_t* __restrict__ h, const float* __restrict__ wsum,
           float* __restrict__ out) {
  __shared__ float bsh[12];
  const int tid = threadIdx.x;
  if (tid < 3) {
    const float invN[3] = {1.f / 51200.f, 1.f / 1024.f, 1.f / 1024.f};
    const int g = tid;
    float s0 = 0.f, s1 = 0.f, s2 = 0.f;
    for (int bkt = 0; bkt < 64; ++bkt) {
      s0 += wsum[g * 256 + bkt * 4 + 0];
      s1 += wsum[g * 256 + bkt * 4 + 1];
      s2 += wsum[g * 256 + bkt * 4 + 2];
    }
    s0 *= invN[g]; s1 *= invN[g]; s2 *= invN[g];
    const float mx = fmaxf(s0, fmaxf(s1, s2));
    const float e0 = expf(s0 - mx), e1 = expf(s1 - mx), e2 = expf(s2 - mx);
    const float inv = 1.f / (e0 + e1 + e2);
    bsh[g * 4 + 0] = e0 * inv;
    bsh[g * 4 + 1] = e1 * inv;
    bsh[g * 4 + 2] = e2 * inv;
  }
  __syncthreads();
  const int t = blockIdx.x * blockDim.x + tid;  // 53248*32
  const int row = t >> 5;
  const int c0 = (t & 31) * 4;
  const int g = (row < 51200) ? 0 : ((row < 52224) ? 1 : 2);
  const float* bt = &bsh[g * 4];
  const size_t base = (size_t)row * 3 * DD + c0;
  const ushort4 ha = *reinterpret_cast<const ushort4*>(&h[base]);
  const ushort4 hb = *reinterpret_cast<const ushort4*>(&h[base + DD]);
  const ushort4 hc = *reinterpret_cast<const ushort4*>(&h[base + 2 * DD]);
  UH u;
  float4 o;
  float va, vb, vc;
  u.s = ha.x; va = __half2float(u.h); u.s = hb.x; vb = __half2float(u.h);
  u.s = hc.x; vc = __half2float(u.h);
  o.x = bt[0] * va + bt[1] * vb + bt[2] * vc;
  u.s = ha.y; va = __half2float(u.h); u.s = hb.y; vb = __half2float(u.h);
  u.s = hc.y; vc = __half2float(u.h);
  o.y = bt[0] * va + bt[1] * vb + bt[2] * vc;
  u.s = ha.z; va = __half2float(u.h); u.s = hb.z; vb = __half2float(u.h);
  u.s = hc.z; vc = __half2float(u.h);
  o.z = bt[0] * va + bt[1] * vb + bt[2] * vc;
  u.s = ha.w; va = __half2float(u.h); u.s = hb.w; vb = __half2float(u.h);
  u.s = hc.w; vc = __half2float(u.h);
  o.w = bt[0] * va + bt[1] * vb + bt[2] * vc;
  *reinterpret_cast<float4*>(&out[(size_t)row * DD + c0]) = o;
}

// ---------------------------------------------------------------------------

extern "C" void kernel_launch(void* const* d_in, const int* in_sizes, int n_in,
                              void* d_out, int out_size, void* d_ws, size_t ws_size,
                              hipStream_t stream) {
  const int*   item     = (const int*)  d_in[0];
  const int*   locs     = (const int*)  d_in[1];
  const int*   times    = (const int*)  d_in[2];
  const float* session  = (const float*)d_in[3];
  const float* loc_emb  = (const float*)d_in[4];
  const float* time_emb = (const float*)d_in[5];
  const float* item_emb = (const float*)d_in[6];
  const int* nb_IL = (const int*)d_in[7];
  const int* nb_TL = (const int*)d_in[8];
  const int* nb_IT = (const int*)d_in[9];
  const int* nb_LT = (const int*)d_in[10];
  const int* nb_II = (const int*)d_in[11];
  const int* nb_LI = (const int*)d_in[12];
  const int* nb_TI = (const int*)d_in[13];
  const float* W_IL = (const float*)d_in[14]; const float* b_IL = (const float*)d_in[15];
  const float* W_TL = (const float*)d_in[16]; const float* b_TL = (const float*)d_in[17];
  const float* W_IT = (const float*)d_in[18]; const float* b_IT = (const float*)d_in[19];
  const float* W_LT = (const float*)d_in[20]; const float* b_LT = (const float*)d_in[21];
  const float* W_II = (const float*)d_in[22]; const float* b_II = (const float*)d_in[23];
  const float* W_LI = (const float*)d_in[24]; const float* b_LI = (const float*)d_in[25];
  const float* W_TI = (const float*)d_in[26]; const float* b_TI = (const float*)d_in[27];
  const float* Ws_l = (const float*)d_in[28]; const float* bs_l = (const float*)d_in[29];
  const float* q_l  = (const float*)d_in[30];
  const float* Ws_t = (const float*)d_in[31]; const float* bs_t = (const float*)d_in[32];
  const float* q_t  = (const float*)d_in[33];
  const float* Ws_i = (const float*)d_in[34]; const float* bs_i = (const float*)d_in[35];
  const float* q_i  = (const float*)d_in[36];

  float* outp = (float*)d_out;

  // ws: wsum/beta(16K) | packed W(544K) | hbuf fp16(40.9M) | fp8 tables(14.3M)
  char* wsb = (char*)d_ws;
  float* wsum  = (float*)wsb;
  ushort_t* pk = (ushort_t*)(wsb + 16384);
  ushort_t* pk_II = pk;
  ushort_t* pk_TI = pk_II + 32768;
  ushort_t* pk_LI = pk_TI + 32768;
  ushort_t* pk_IL = pk_LI + 32768;
  ushort_t* pk_TL = pk_IL + 32768;
  ushort_t* pk_IT = pk_TL + 32768;
  ushort_t* pk_LT = pk_IT + 32768;
  ushort_t* pk_Wi = pk_LT + 32768;
  ushort_t* pk_Wl = pk_Wi + 16384;
  ushort_t* pk_Wt = pk_Wl + 16384;
  ushort_t* hbuf  = pk_Wt + 16384;
  uchar_t* item_8 = (uchar_t*)(hbuf + (size_t)53248 * 3 * DD);
  uchar_t* loc_8  = item_8 + (size_t)100000 * DD;
  uchar_t* time_8 = loc_8 + (size_t)10000 * DD;

  (void)hipMemsetAsync(d_ws, 0, 16384, stream);

  PrepArgs pp;
  pp.item = item_emb; pp.loc = loc_emb; pp.timet = time_emb;
  pp.dst8 = item_8;
  pp.wsrc[0] = W_II; pp.wsrc[1] = W_TI; pp.wsrc[2] = W_LI;
  pp.wsrc[3] = W_IL; pp.wsrc[4] = W_TL; pp.wsrc[5] = W_IT; pp.wsrc[6] = W_LT;
  pp.wsrc[7] = Ws_i; pp.wsrc[8] = Ws_l; pp.wsrc[9] = Ws_t;
  pp.wdst = pk;
  k_prep<<<dim3(7136), dim3(256), 0, stream>>>(pp);

  ushort_t* h_items = hbuf;
  ushort_t* h_locs  = hbuf + (size_t)51200 * 3 * DD;
  ushort_t* h_times = hbuf + (size_t)52224 * 3 * DD;

  MegaArgs ma;
  ma.item_idx = item; ma.item_f = item_emb;
  ma.nbI[0] = nb_II; ma.nbI[1] = nb_TI; ma.nbI[2] = nb_LI;
  ma.embI[0] = item_8; ma.embI[1] = time_8; ma.embI[2] = loc_8;
  ma.pWI[0] = pk_II; ma.pWI[1] = pk_TI; ma.pWI[2] = pk_LI;
  ma.bI[0] = b_II; ma.bI[1] = b_TI; ma.bI[2] = b_LI;
  ma.pWsI = pk_Wi; ma.bsI = bs_i; ma.qI = q_i;
  ma.hI = h_items; ma.wsumI = wsum + 0;
  ma.sidx[0] = locs;  ma.sidx[1] = times;
  ma.st_f[0] = loc_emb; ma.st_f[1] = time_emb;
  ma.nbS[0][0] = nb_IL; ma.nbS[0][1] = nb_TL;
  ma.nbS[1][0] = nb_IT; ma.nbS[1][1] = nb_LT;
  ma.embS[0][0] = item_8; ma.embS[0][1] = time_8;
  ma.embS[1][0] = item_8; ma.embS[1][1] = loc_8;
  ma.pWS[0][0] = pk_IL; ma.pWS[0][1] = pk_TL;
  ma.pWS[1][0] = pk_IT; ma.pWS[1][1] = pk_LT;
  ma.bS[0][0] = b_IL; ma.bS[0][1] = b_TL;
  ma.bS[1][0] = b_IT; ma.bS[1][1] = b_LT;
  ma.pWsS[0] = pk_Wl; ma.pWsS[1] = pk_Wt;
  ma.bsS[0] = bs_l; ma.bsS[1] = bs_t;
  ma.qS[0] = q_l; ma.qS[1] = q_t;
  ma.session = session;
  ma.hS[0] = h_locs; ma.hS[1] = h_times;
  ma.wsumS[0] = wsum + 256; ma.wsumS[1] = wsum + 512;
  k_mega<<<dim3(64 + 51200 / TRR), dim3(NT), 0, stream>>>(ma);

  k_out<<<dim3((53248 * 32) / 256), dim3(256), 0, stream>>>(hbuf, wsum, outp);
}